// Round 3
// baseline (55.312 us; speedup 1.0000x reference)
//
#include <hip/hip_runtime.h>
#include <math.h>

// x: [32,3,512,512] f32.
// Register-resident row sweep, 8 cols/lane (wave spans all 512 columns).
// Sobel (separable) -> mag -> 3x3 avgpool (zero-pad, /9) -> f32 partial
// sum/sumsq per wave -> double partials -> stats+MLP kernel.
// Grid: (4, 96) x 256 threads = 16 waves per (b,c), 32 output rows each.

__global__ __launch_bounds__(256) void sobel_pool_stats(
    const float* __restrict__ x, double* __restrict__ parts) {
  const int tid = threadIdx.x;
  const int lane = tid & 63;
  const int wib = tid >> 6;
  const int bc = blockIdx.y;                 // 0..95
  const int wloc = blockIdx.x * 4 + wib;     // 0..15
  const int row0 = wloc * 32;

  const float* __restrict__ xptr = x + (size_t)bc * (512 * 512) + lane * 8;

  float xA[8], xB[8], xC[8];
  float mag_m[8], mag_c[8], mag_p[8];

  auto load8 = [&](int r, float* o) {
    if ((unsigned)r < 512u) {
      const float4* p = (const float4*)(xptr + r * 512);
      float4 u = p[0], v = p[1];
      o[0] = u.x; o[1] = u.y; o[2] = u.z; o[3] = u.w;
      o[4] = v.x; o[5] = v.y; o[6] = v.z; o[7] = v.w;
    } else {
#pragma unroll
      for (int j = 0; j < 8; ++j) o[j] = 0.f;
    }
  };

  // Sobel magnitude for one mag-row given 3 x-rows; 0 if mag-row OOB.
  auto magrow8 = [&](const float* xm, const float* x0, const float* xp,
                     int mr, float* mg) {
    float a[8], b[8];
#pragma unroll
    for (int j = 0; j < 8; ++j) {
      a[j] = (xm[j] + xp[j]) + 2.f * x0[j];  // vertical [1,2,1]
      b[j] = xm[j] - xp[j];                  // vertical [1,0,-1]
    }
    float aL = __shfl_up(a[7], 1), aR = __shfl_down(a[0], 1);
    float bL = __shfl_up(b[7], 1), bR = __shfl_down(b[0], 1);
    if (lane == 0) { aL = 0.f; bL = 0.f; }
    if (lane == 63) { aR = 0.f; bR = 0.f; }
    const bool rowok = ((unsigned)mr < 512u);
#pragma unroll
    for (int j = 0; j < 8; ++j) {
      float am = (j == 0) ? aL : a[j - 1];
      float ap = (j == 7) ? aR : a[j + 1];
      float bm = (j == 0) ? bL : b[j - 1];
      float bp = (j == 7) ? bR : b[j + 1];
      float gx = am - ap;                    // horizontal [1,0,-1]
      float gy = (bm + bp) + 2.f * b[j];     // horizontal [1,2,1]
      float m = sqrtf(gx * gx + gy * gy + 1e-6f);
      mg[j] = rowok ? m : 0.f;
    }
  };

  // warmup: x rows row0-2..row0+1, mag rows row0-1, row0
  load8(row0 - 2, xA);
  load8(row0 - 1, xB);
  load8(row0, xC);
  magrow8(xA, xB, xC, row0 - 1, mag_m);
#pragma unroll
  for (int j = 0; j < 8; ++j) xA[j] = xB[j];   // xA=x(r-1)... rotate
#pragma unroll
  for (int j = 0; j < 8; ++j) xB[j] = xC[j];
  load8(row0 + 1, xC);
  magrow8(xA, xB, xC, row0, mag_c);

  float s = 0.f, ss = 0.f;

#pragma unroll 4
  for (int i = 0; i < 32; ++i) {
    const int r = row0 + i;
    // advance x window: need rows r, r+1, r+2 for mag row r+1
#pragma unroll
    for (int j = 0; j < 8; ++j) xA[j] = xB[j];
#pragma unroll
    for (int j = 0; j < 8; ++j) xB[j] = xC[j];
    load8(r + 2, xC);
    magrow8(xA, xB, xC, r + 1, mag_p);

    float cs[8];
#pragma unroll
    for (int j = 0; j < 8; ++j) cs[j] = (mag_m[j] + mag_p[j]) + mag_c[j];
    float csL = __shfl_up(cs[7], 1), csR = __shfl_down(cs[0], 1);
    if (lane == 0) csL = 0.f;
    if (lane == 63) csR = 0.f;
#pragma unroll
    for (int j = 0; j < 8; ++j) {
      float cm = (j == 0) ? csL : cs[j - 1];
      float cp = (j == 7) ? csR : cs[j + 1];
      float pooled = ((cm + cp) + cs[j]) * (1.f / 9.f);
      s += pooled;
      ss += pooled * pooled;
    }
#pragma unroll
    for (int j = 0; j < 8; ++j) mag_m[j] = mag_c[j];
#pragma unroll
    for (int j = 0; j < 8; ++j) mag_c[j] = mag_p[j];
  }

  // wave reduction in double (exact past this point)
  double ds = (double)s, dss = (double)ss;
  for (int off = 32; off > 0; off >>= 1) {
    ds += __shfl_down(ds, off);
    dss += __shfl_down(dss, off);
  }
  if (lane == 0) {
    size_t idx = ((size_t)bc * 16 + wloc) * 2;
    parts[idx] = ds;
    parts[idx + 1] = dss;
  }
}

// Reduce 16 wave-partials per (b,c), feats [32,6]=[m0,s0,m1,s1,m2,s2], MLP.
__global__ __launch_bounds__(256) void stats_mlp(
    const double* __restrict__ parts,
    const float* __restrict__ w1, const float* __restrict__ b1,
    const float* __restrict__ w2, const float* __restrict__ b2,
    float* __restrict__ out) {
  __shared__ float feats[32 * 6];
  __shared__ float hbuf[32 * 32];
  const int tid = threadIdx.x;

  if (tid < 96) {
    int b = tid / 3;
    int ch = tid - b * 3;
    double s = 0.0, ss = 0.0;
    const double* p = parts + (size_t)tid * 32;  // 16 waves * 2 doubles
#pragma unroll
    for (int t = 0; t < 16; ++t) {
      s += p[2 * t];
      ss += p[2 * t + 1];
    }
    const double N = 262144.0;
    double mean = s / N;
    double var = (ss - s * s / N) / (N - 1.0);
    if (var < 0.0) var = 0.0;
    feats[b * 6 + 2 * ch] = (float)mean;
    feats[b * 6 + 2 * ch + 1] = (float)sqrt(var);
  }
  __syncthreads();

  for (int idx = tid; idx < 32 * 32; idx += 256) {
    int i = idx >> 5, j = idx & 31;
    float acc = b1[j];
#pragma unroll
    for (int k = 0; k < 6; ++k) acc += feats[i * 6 + k] * w1[j * 6 + k];
    hbuf[idx] = acc > 0.f ? acc : 0.f;
  }
  __syncthreads();

  for (int idx = tid; idx < 2048; idx += 256) {
    int i = idx >> 6, o = idx & 63;
    float acc = b2[o];
#pragma unroll
    for (int j = 0; j < 32; ++j) acc += hbuf[i * 32 + j] * w2[o * 32 + j];
    out[idx] = acc;
  }
}

extern "C" void kernel_launch(void* const* d_in, const int* in_sizes, int n_in,
                              void* d_out, int out_size, void* d_ws, size_t ws_size,
                              hipStream_t stream) {
  const float* x = (const float*)d_in[0];
  const float* w1 = (const float*)d_in[1];
  const float* b1 = (const float*)d_in[2];
  const float* w2 = (const float*)d_in[3];
  const float* b2 = (const float*)d_in[4];
  float* out = (float*)d_out;
  double* parts = (double*)d_ws;  // 96*16*2 doubles = 24576 B

  dim3 grid(4, 96);
  sobel_pool_stats<<<grid, 256, 0, stream>>>(x, parts);
  stats_mlp<<<1, 256, 0, stream>>>(parts, w1, b1, w2, b2, out);
}

// Round 4
// 48.248 us; speedup vs baseline: 1.1464x; 1.1464x over previous
//
#include <hip/hip_runtime.h>
#include <math.h>

// x: [32,3,512,512] f32.
// Register-resident row sweep, 8 cols/lane (wave spans all 512 columns).
// Sobel (separable) -> mag -> 3x3 avgpool (zero-pad, /9) -> f32 partial
// sum/sumsq per wave -> double partials -> stats+MLP kernel.
// Occupancy fix vs r3: 8 output rows per wave -> 96*64 = 6144 waves.
// Grid: (16, 96) x 256 threads.

__global__ __launch_bounds__(256) void sobel_pool_stats(
    const float* __restrict__ x, double* __restrict__ parts) {
  const int tid = threadIdx.x;
  const int lane = tid & 63;
  const int wib = tid >> 6;
  const int bc = blockIdx.y;                 // 0..95
  const int wloc = blockIdx.x * 4 + wib;     // 0..63
  const int row0 = wloc * 8;

  const float* __restrict__ xptr = x + (size_t)bc * (512 * 512) + lane * 8;

  float xA[8], xB[8], xC[8];
  float mag_m[8], mag_c[8], mag_p[8];

  auto load8 = [&](int r, float* o) {
    if ((unsigned)r < 512u) {
      const float4* p = (const float4*)(xptr + r * 512);
      float4 u = p[0], v = p[1];
      o[0] = u.x; o[1] = u.y; o[2] = u.z; o[3] = u.w;
      o[4] = v.x; o[5] = v.y; o[6] = v.z; o[7] = v.w;
    } else {
#pragma unroll
      for (int j = 0; j < 8; ++j) o[j] = 0.f;
    }
  };

  // Sobel magnitude for one mag-row given 3 x-rows; 0 if mag-row OOB.
  auto magrow8 = [&](const float* xm, const float* x0, const float* xp,
                     int mr, float* mg) {
    float a[8], b[8];
#pragma unroll
    for (int j = 0; j < 8; ++j) {
      a[j] = (xm[j] + xp[j]) + 2.f * x0[j];  // vertical [1,2,1]
      b[j] = xm[j] - xp[j];                  // vertical [1,0,-1]
    }
    float aL = __shfl_up(a[7], 1), aR = __shfl_down(a[0], 1);
    float bL = __shfl_up(b[7], 1), bR = __shfl_down(b[0], 1);
    if (lane == 0) { aL = 0.f; bL = 0.f; }
    if (lane == 63) { aR = 0.f; bR = 0.f; }
    const bool rowok = ((unsigned)mr < 512u);
#pragma unroll
    for (int j = 0; j < 8; ++j) {
      float am = (j == 0) ? aL : a[j - 1];
      float ap = (j == 7) ? aR : a[j + 1];
      float bm = (j == 0) ? bL : b[j - 1];
      float bp = (j == 7) ? bR : b[j + 1];
      float gx = am - ap;                    // horizontal [1,0,-1]
      float gy = (bm + bp) + 2.f * b[j];     // horizontal [1,2,1]
      float m = sqrtf(gx * gx + gy * gy + 1e-6f);
      mg[j] = rowok ? m : 0.f;
    }
  };

  // warmup: x rows row0-2..row0+1, mag rows row0-1, row0
  load8(row0 - 2, xA);
  load8(row0 - 1, xB);
  load8(row0, xC);
  magrow8(xA, xB, xC, row0 - 1, mag_m);
#pragma unroll
  for (int j = 0; j < 8; ++j) xA[j] = xB[j];
#pragma unroll
  for (int j = 0; j < 8; ++j) xB[j] = xC[j];
  load8(row0 + 1, xC);
  magrow8(xA, xB, xC, row0, mag_c);

  float s = 0.f, ss = 0.f;

#pragma unroll
  for (int i = 0; i < 8; ++i) {
    const int r = row0 + i;
#pragma unroll
    for (int j = 0; j < 8; ++j) xA[j] = xB[j];
#pragma unroll
    for (int j = 0; j < 8; ++j) xB[j] = xC[j];
    load8(r + 2, xC);
    magrow8(xA, xB, xC, r + 1, mag_p);

    float cs[8];
#pragma unroll
    for (int j = 0; j < 8; ++j) cs[j] = (mag_m[j] + mag_p[j]) + mag_c[j];
    float csL = __shfl_up(cs[7], 1), csR = __shfl_down(cs[0], 1);
    if (lane == 0) csL = 0.f;
    if (lane == 63) csR = 0.f;
#pragma unroll
    for (int j = 0; j < 8; ++j) {
      float cm = (j == 0) ? csL : cs[j - 1];
      float cp = (j == 7) ? csR : cs[j + 1];
      float pooled = ((cm + cp) + cs[j]) * (1.f / 9.f);
      s += pooled;
      ss += pooled * pooled;
    }
#pragma unroll
    for (int j = 0; j < 8; ++j) mag_m[j] = mag_c[j];
#pragma unroll
    for (int j = 0; j < 8; ++j) mag_c[j] = mag_p[j];
  }

  // wave reduction in double (exact past this point)
  double ds = (double)s, dss = (double)ss;
  for (int off = 32; off > 0; off >>= 1) {
    ds += __shfl_down(ds, off);
    dss += __shfl_down(dss, off);
  }
  if (lane == 0) {
    size_t idx = ((size_t)bc * 64 + wloc) * 2;
    parts[idx] = ds;
    parts[idx + 1] = dss;
  }
}

// Reduce 64 wave-partials per (b,c), feats [32,6]=[m0,s0,m1,s1,m2,s2], MLP.
__global__ __launch_bounds__(256) void stats_mlp(
    const double* __restrict__ parts,
    const float* __restrict__ w1, const float* __restrict__ b1,
    const float* __restrict__ w2, const float* __restrict__ b2,
    float* __restrict__ out) {
  __shared__ float feats[32 * 6];
  __shared__ float hbuf[32 * 32];
  const int tid = threadIdx.x;

  if (tid < 96) {
    int b = tid / 3;
    int ch = tid - b * 3;
    double s = 0.0, ss = 0.0;
    const double* p = parts + (size_t)tid * 128;  // 64 waves * 2 doubles
#pragma unroll
    for (int t = 0; t < 64; ++t) {
      s += p[2 * t];
      ss += p[2 * t + 1];
    }
    const double N = 262144.0;
    double mean = s / N;
    double var = (ss - s * s / N) / (N - 1.0);
    if (var < 0.0) var = 0.0;
    feats[b * 6 + 2 * ch] = (float)mean;
    feats[b * 6 + 2 * ch + 1] = (float)sqrt(var);
  }
  __syncthreads();

  for (int idx = tid; idx < 32 * 32; idx += 256) {
    int i = idx >> 5, j = idx & 31;
    float acc = b1[j];
#pragma unroll
    for (int k = 0; k < 6; ++k) acc += feats[i * 6 + k] * w1[j * 6 + k];
    hbuf[idx] = acc > 0.f ? acc : 0.f;
  }
  __syncthreads();

  for (int idx = tid; idx < 2048; idx += 256) {
    int i = idx >> 6, o = idx & 63;
    float acc = b2[o];
#pragma unroll
    for (int j = 0; j < 32; ++j) acc += hbuf[i * 32 + j] * w2[o * 32 + j];
    out[idx] = acc;
  }
}

extern "C" void kernel_launch(void* const* d_in, const int* in_sizes, int n_in,
                              void* d_out, int out_size, void* d_ws, size_t ws_size,
                              hipStream_t stream) {
  const float* x = (const float*)d_in[0];
  const float* w1 = (const float*)d_in[1];
  const float* b1 = (const float*)d_in[2];
  const float* w2 = (const float*)d_in[3];
  const float* b2 = (const float*)d_in[4];
  float* out = (float*)d_out;
  double* parts = (double*)d_ws;  // 96*64*2 doubles = 98304 B

  dim3 grid(16, 96);
  sobel_pool_stats<<<grid, 256, 0, stream>>>(x, parts);
  stats_mlp<<<1, 256, 0, stream>>>(parts, w1, b1, w2, b2, out);
}